// Round 5
// baseline (374.731 us; speedup 1.0000x reference)
//
#include <hip/hip_runtime.h>
#include <hip/hip_bf16.h>

// Linear4bit NF4: y[2048,11008] = x[2048,4096] @ dequant(W)[11008,4096]^T + bias
// Phase 1: merged coalesced dequant W (NF4->bf16) + convert x (fp32->bf16) into d_ws.
// Phase 2: bf16 GEMM, 128x256x64 block tile, 4 waves, 64x128 wave tile
//   (acc[4][8]) -> 32 MFMA per 12 ds_read_b128 (was 16:8) to lift the LDS-read
//   wall; XOR-swizzled LDS (round 4: conflicts 6.76e7 -> 0) preserved.

#define IN_F   4096
#define OUT_F  11008
#define M_ROWS 2048
#define BM 128
#define BN 256
#define BK 64
#define LDSS 72   // fused-fallback padded stride

typedef short  s16x8 __attribute__((ext_vector_type(8)));
typedef unsigned short u16x8 __attribute__((ext_vector_type(8)));
typedef float  f32x4 __attribute__((ext_vector_type(4)));
typedef int    i32x4 __attribute__((ext_vector_type(4)));
typedef unsigned int u32x4 __attribute__((ext_vector_type(4)));

__device__ const float NF4_C[16] = {
    -1.0f, -0.6961928009986877f, -0.5250730514526367f, -0.39491748809814453f,
    -0.28444138169288635f, -0.18477343022823334f, -0.09105003625154495f, 0.0f,
    0.07958029955625534f, 0.16093020141124725f, 0.24611230194568634f,
    0.33791524171829224f, 0.44070982933044434f, 0.5626170039176941f,
    0.7229568362236023f, 1.0f};

static __device__ __forceinline__ unsigned short f2bf(float f) {
    union { float f; unsigned int u; } c;
    c.f = f;
    unsigned int u = c.u;
    u += 0x7fffu + ((u >> 16) & 1u);
    return (unsigned short)(u >> 16);
}

static __device__ __forceinline__ void gload_lds16(const void* g, void* l) {
    __builtin_amdgcn_global_load_lds(
        (const __attribute__((address_space(1))) void*)g,
        (__attribute__((address_space(3))) void*)l, 16, 0, 0);
}

// ---------------- phase 1 (merged, coalesced): dequant W + convert x ----------
#define DQ_BLOCKS 11008
#define CV_BLOCKS 4096

__global__ __launch_bounds__(256)
void prep_kernel(const float* __restrict__ x,
                 const int* __restrict__ packed,
                 const float* __restrict__ absmax,
                 unsigned short* __restrict__ xb,
                 unsigned short* __restrict__ wb) {
    if (blockIdx.x < DQ_BLOCKS) {
        __shared__ float tab_hi[256];
        __shared__ float tab_lo[256];
        tab_hi[threadIdx.x] = NF4_C[threadIdx.x >> 4];
        tab_lo[threadIdx.x] = NF4_C[threadIdx.x & 15];
        __syncthreads();

        const size_t u0 = (size_t)blockIdx.x * 512 + threadIdx.x;
#pragma unroll
        for (int h = 0; h < 2; ++h) {
            const size_t u = u0 + h * 256;
            i32x4 v = __builtin_nontemporal_load(
                reinterpret_cast<const i32x4*>(packed) + u);
            const float s = absmax[u >> 3];
            unsigned int ow[4];
#pragma unroll
            for (int j = 0; j < 4; ++j) {
                const int b = v[j] & 0xFF;
                ow[j] = (unsigned int)f2bf(tab_hi[b] * s)
                      | ((unsigned int)f2bf(tab_lo[b] * s) << 16);
            }
            *(reinterpret_cast<u32x4*>(wb) + u) = (u32x4){ow[0], ow[1], ow[2], ow[3]};
        }
    } else {
        const size_t u0 = (size_t)(blockIdx.x - DQ_BLOCKS) * 512 + threadIdx.x;
#pragma unroll
        for (int h = 0; h < 2; ++h) {
            const size_t u = u0 + h * 256;
            f32x4 v = __builtin_nontemporal_load(
                reinterpret_cast<const f32x4*>(x) + u);
            ushort4 o;
            o.x = f2bf(v[0]); o.y = f2bf(v[1]); o.z = f2bf(v[2]); o.w = f2bf(v[3]);
            *(reinterpret_cast<ushort4*>(xb) + u) = o;
        }
    }
}

// ---------------- phase 2: bf16 GEMM, 128x256 tile, 64x128 wave tile ----------
__global__ __launch_bounds__(256, 2)
void gemm_bt_kernel(const unsigned short* __restrict__ xb,   // [2048,4096] bf16
                    const unsigned short* __restrict__ wb,   // [11008,4096] bf16
                    const float* __restrict__ bias,
                    float* __restrict__ out) {
    __shared__ __align__(16) unsigned short As[BM * BK];   // 16 KB
    __shared__ __align__(16) unsigned short Bs[BN * BK];   // 32 KB

    const int tid  = threadIdx.x;
    const int lane = tid & 63;
    const int wave = tid >> 6;
    const int quad = lane >> 4;
    const int l16  = lane & 15;
    const int wm = wave & 1;     // 64-row half
    const int wn = wave >> 1;    // 128-col half

    // grid (M-tiles=16, N-tiles=43): consecutive blocks share a B-panel.
    const int mBase = blockIdx.x * BM;
    const int nBase = blockIdx.y * BN;

    // staging: LDS[row][c] holds global 16B-chunk (c ^ (row&7)) of that row.
    const int srow = tid >> 3;           // 0..31 (+32*i)
    const int sc   = tid & 7;
    const int scS  = sc ^ (srow & 7);

    f32x4 acc[4][8];
#pragma unroll
    for (int mi = 0; mi < 4; ++mi)
#pragma unroll
        for (int ni = 0; ni < 8; ++ni)
            acc[mi][ni] = (f32x4){0.f, 0.f, 0.f, 0.f};

    const unsigned short* aSrc = xb + (size_t)(mBase + srow) * IN_F + scS * 8;
    const unsigned short* bSrc = wb + (size_t)(nBase + srow) * IN_F + scS * 8;

    const int sw = l16 & 7;   // reader un-swizzle key

    for (int kt = 0; kt < IN_F / BK; ++kt) {
        const int k0 = kt * BK;
        __syncthreads();
#pragma unroll
        for (int i = 0; i < 4; ++i)
            gload_lds16(aSrc + (size_t)i * 32 * IN_F + k0, &As[(i * 32 + srow) * BK + sc * 8]);
#pragma unroll
        for (int i = 0; i < 8; ++i)
            gload_lds16(bSrc + (size_t)i * 32 * IN_F + k0, &Bs[(i * 32 + srow) * BK + sc * 8]);
        __syncthreads();

#pragma unroll
        for (int kk = 0; kk < 2; ++kk) {
            const int rd = ((kk * 4 + quad) ^ sw) * 8;
            s16x8 af[4], bfr[8];
#pragma unroll
            for (int mi = 0; mi < 4; ++mi)
                af[mi] = *reinterpret_cast<const s16x8*>(
                    &As[(wm * 64 + mi * 16 + l16) * BK + rd]);
#pragma unroll
            for (int ni = 0; ni < 8; ++ni)
                bfr[ni] = *reinterpret_cast<const s16x8*>(
                    &Bs[(wn * 128 + ni * 16 + l16) * BK + rd]);
#pragma unroll
            for (int mi = 0; mi < 4; ++mi)
#pragma unroll
                for (int ni = 0; ni < 8; ++ni)
                    acc[mi][ni] = __builtin_amdgcn_mfma_f32_16x16x32_bf16(
                        af[mi], bfr[ni], acc[mi][ni], 0, 0, 0);
        }
    }

    float bv[8];
#pragma unroll
    for (int ni = 0; ni < 8; ++ni)
        bv[ni] = bias[nBase + wn * 128 + ni * 16 + l16];
#pragma unroll
    for (int mi = 0; mi < 4; ++mi) {
        const int rbase = mBase + wm * 64 + mi * 16 + quad * 4;
#pragma unroll
        for (int ni = 0; ni < 8; ++ni) {
            const int col = nBase + wn * 128 + ni * 16 + l16;
#pragma unroll
            for (int r = 0; r < 4; ++r)
                __builtin_nontemporal_store(acc[mi][ni][r] + bv[ni],
                    &out[(size_t)(rbase + r) * OUT_F + col]);
        }
    }
}

// ---------------- fallback: fused kernel (small ws) ----------------
__global__ __launch_bounds__(256, 2)
void nf4_linear_fused(const float* __restrict__ x,
                      const int* __restrict__ packed,
                      const float* __restrict__ absmax,
                      const float* __restrict__ bias,
                      float* __restrict__ out) {
    __shared__ __align__(16) unsigned short As[BM * LDSS];
    __shared__ __align__(16) unsigned short Bs[128 * LDSS];
    __shared__ float2 tab[256];

    const int tid  = threadIdx.x;
    const int lane = tid & 63;
    const int wave = tid >> 6;
    const int quad = lane >> 4;
    const int l16  = lane & 15;
    const int wm = wave & 1;
    const int wn = wave >> 1;
    const int mBase = blockIdx.y * BM;
    const int nBase = blockIdx.x * 128;

    tab[tid] = make_float2(NF4_C[tid >> 4], NF4_C[tid & 15]);

    f32x4 acc[4][4];
#pragma unroll
    for (int mi = 0; mi < 4; ++mi)
#pragma unroll
        for (int ni = 0; ni < 4; ++ni)
            acc[mi][ni] = (f32x4){0.f, 0.f, 0.f, 0.f};

    const int brow  = tid >> 1;
    const int bhalf = tid & 1;
    const int ng    = nBase + brow;

    for (int kt = 0; kt < IN_F / BK; ++kt) {
        const int k0 = kt * BK;
        __syncthreads();
#pragma unroll
        for (int i = 0; i < 4; ++i) {
            int gid = tid + i * 256;
            int row = gid >> 3;
            int c8  = gid & 7;
            const float4* src = reinterpret_cast<const float4*>(
                x + (size_t)(mBase + row) * IN_F + k0 + c8 * 8);
            float4 v0 = src[0];
            float4 v1 = src[1];
            u16x8 o;
            o[0] = f2bf(v0.x); o[1] = f2bf(v0.y); o[2] = f2bf(v0.z); o[3] = f2bf(v0.w);
            o[4] = f2bf(v1.x); o[5] = f2bf(v1.y); o[6] = f2bf(v1.z); o[7] = f2bf(v1.w);
            *reinterpret_cast<u16x8*>(&As[row * LDSS + c8 * 8]) = o;
        }
        {
            const float scale = absmax[(size_t)ng * 64 + (k0 >> 6)];
            const int4* bp = reinterpret_cast<const int4*>(
                packed + (size_t)ng * (IN_F / 2) + (k0 >> 1) + bhalf * 16);
            const int colw = bhalf * 32;
#pragma unroll
            for (int c = 0; c < 4; ++c) {
                int4 v = bp[c];
                int vs[4] = {v.x, v.y, v.z, v.w};
                unsigned int ow[4];
#pragma unroll
                for (int j = 0; j < 4; ++j) {
                    float2 t = tab[vs[j] & 0xFF];
                    ow[j] = (unsigned int)f2bf(t.x * scale)
                          | ((unsigned int)f2bf(t.y * scale) << 16);
                }
                *reinterpret_cast<uint4*>(&Bs[brow * LDSS + colw + c * 8]) =
                    *reinterpret_cast<const uint4*>(ow);
            }
        }
        __syncthreads();

#pragma unroll
        for (int kk = 0; kk < 2; ++kk) {
            const int kof = kk * 32 + quad * 8;
            s16x8 af[4], bfr[4];
#pragma unroll
            for (int mi = 0; mi < 4; ++mi)
                af[mi] = *reinterpret_cast<const s16x8*>(
                    &As[(wm * 64 + mi * 16 + l16) * LDSS + kof]);
#pragma unroll
            for (int ni = 0; ni < 4; ++ni)
                bfr[ni] = *reinterpret_cast<const s16x8*>(
                    &Bs[(wn * 64 + ni * 16 + l16) * LDSS + kof]);
#pragma unroll
            for (int mi = 0; mi < 4; ++mi)
#pragma unroll
                for (int ni = 0; ni < 4; ++ni)
                    acc[mi][ni] = __builtin_amdgcn_mfma_f32_16x16x32_bf16(
                        af[mi], bfr[ni], acc[mi][ni], 0, 0, 0);
        }
    }

    float bv[4];
#pragma unroll
    for (int ni = 0; ni < 4; ++ni)
        bv[ni] = bias[nBase + wn * 64 + ni * 16 + l16];
#pragma unroll
    for (int mi = 0; mi < 4; ++mi) {
        const int rbase = mBase + wm * 64 + mi * 16 + quad * 4;
#pragma unroll
        for (int ni = 0; ni < 4; ++ni) {
            const int col = nBase + wn * 64 + ni * 16 + l16;
#pragma unroll
            for (int r = 0; r < 4; ++r)
                out[(size_t)(rbase + r) * OUT_F + col] = acc[mi][ni][r] + bv[ni];
        }
    }
}

extern "C" void kernel_launch(void* const* d_in, const int* in_sizes, int n_in,
                              void* d_out, int out_size, void* d_ws, size_t ws_size,
                              hipStream_t stream) {
    const float* x      = (const float*)d_in[0];
    const int*   packed = (const int*)d_in[1];
    const float* absmax = (const float*)d_in[2];
    const float* bias   = (const float*)d_in[3];
    float* out = (float*)d_out;

    const size_t xb_bytes = (size_t)M_ROWS * IN_F * 2;
    const size_t wb_bytes = (size_t)OUT_F * IN_F * 2;
    if (ws_size >= xb_bytes + wb_bytes) {
        unsigned short* xb = (unsigned short*)d_ws;
        unsigned short* wb = (unsigned short*)((char*)d_ws + xb_bytes);
        prep_kernel<<<dim3(DQ_BLOCKS + CV_BLOCKS), dim3(256), 0, stream>>>(
            x, packed, absmax, xb, wb);
        gemm_bt_kernel<<<dim3(M_ROWS / BM, OUT_F / BN), dim3(256), 0, stream>>>(
            xb, wb, bias, out);
    } else {
        nf4_linear_fused<<<dim3(OUT_F / 128, M_ROWS / BM), dim3(256), 0, stream>>>(
            x, packed, absmax, bias, out);
    }
}